// Round 2
// baseline (243.471 us; speedup 1.0000x reference)
//
#include <hip/hip_runtime.h>

#define BATCH 4
#define CHAN 128
#define HGT 96
#define WID 160
#define TILE 32
#define CC 4
#define NCHUNK (CHAN / CC)   // 32
#define THREADS 256
#define TGT_W 44             // 40 used + pad (11 float4 groups, odd -> 2-way max)
#define SRC_W 36             // 32 used + pad (9 float4 groups, odd -> 2-way max)
#define NT 5                 // tgt float4 loads/thread/chunk (4*32*10 / 256)
#define NS 4                 // src float4 loads/thread/chunk (4*32*8 / 256)

// Output channel index for displacement (dy,dx), matching _displacements(4) order.
__device__ __forceinline__ int chan_of(int dy, int dx) {
    if (dy == 0 && dx == 0) return 0;
    if (dx == 0) { int i = dy < 0 ? -dy : dy; return 1 + (i - 1) * 20 + (dy < 0 ? 0 : 1); }
    if (dy == 0) { int i = dx < 0 ? -dx : dx; return 1 + (i - 1) * 20 + (dx < 0 ? 2 : 3); }
    int i = dy < 0 ? -dy : dy;
    int j = dx < 0 ? -dx : dx;
    int s = (dy < 0) ? (dx < 0 ? 0 : 2) : (dx < 0 ? 3 : 1);
    return 1 + (i - 1) * 20 + 4 + (j - 1) * 4 + s;
}

__global__ __launch_bounds__(THREADS, 2)
void cost_volume_kernel(const float* __restrict__ src,
                        const float* __restrict__ tgt,
                        float* __restrict__ out) {
    __shared__ __align__(16) float s_tgt[CC][TILE][TGT_W];  // 22528 B
    __shared__ __align__(16) float s_src[CC][TILE][SRC_W];  // 18432 B -> 40 KB total

    const int tid = threadIdx.x;
    const int tx  = tid & 7;          // 4 px each along x
    const int ty  = tid >> 3;         // 0..31
    const int px0 = tx * 4;
    const int x0  = blockIdx.x * TILE;
    const int y0  = blockIdx.y * TILE;
    const int b   = blockIdx.z / 9;
    const int dy  = (int)(blockIdx.z % 9) - 4;   // one dy per block

    // --- precompute staging descriptors (all divisions hoisted out of the loop)
    int t_goff[NT], t_loff[NT];
    bool t_ok[NT];
    #pragma unroll
    for (int k = 0; k < NT; ++k) {
        int idx = k * THREADS + tid;   // 0..1279
        int q   = idx % 10;            // float4 col within 40-wide row
        int rc  = idx / 10;            // 0..127
        int c   = rc >> 5;
        int r   = rc & 31;
        int gy  = y0 + dy + r;
        int gx  = x0 - 4 + q * 4;
        t_ok[k] = ((unsigned)gy < (unsigned)HGT) && ((unsigned)gx < (unsigned)WID);
        int cy  = t_ok[k] ? gy : 0;
        int cx  = t_ok[k] ? gx : 0;
        t_goff[k] = ((b * CHAN + c) * HGT + cy) * WID + cx;
        t_loff[k] = (c * TILE + r) * TGT_W + q * 4;
    }
    int s_goff[NS], s_loff[NS];
    #pragma unroll
    for (int k = 0; k < NS; ++k) {
        int idx = k * THREADS + tid;   // 0..1023
        int q   = idx & 7;
        int r   = (idx >> 3) & 31;
        int c   = idx >> 8;
        s_goff[k] = ((b * CHAN + c) * HGT + (y0 + r)) * WID + (x0 + q * 4);
        s_loff[k] = (c * TILE + r) * SRC_W + q * 4;
    }

    const int cstride = CC * HGT * WID;

    // --- prefetch chunk 0 into registers
    float4 pt[NT], ps[NS];
    #pragma unroll
    for (int k = 0; k < NT; ++k)
        pt[k] = t_ok[k] ? *reinterpret_cast<const float4*>(tgt + t_goff[k])
                        : make_float4(0.f, 0.f, 0.f, 0.f);
    #pragma unroll
    for (int k = 0; k < NS; ++k)
        ps[k] = *reinterpret_cast<const float4*>(src + s_goff[k]);

    float4 acc[9];
    #pragma unroll
    for (int d = 0; d < 9; ++d) acc[d] = make_float4(0.f, 0.f, 0.f, 0.f);

    #pragma unroll 1
    for (int ch = 0; ch < NCHUNK; ++ch) {
        __syncthreads();   // previous chunk's consumers done; LDS reusable
        #pragma unroll
        for (int k = 0; k < NT; ++k)
            *reinterpret_cast<float4*>(&((float*)s_tgt)[t_loff[k]]) = pt[k];
        #pragma unroll
        for (int k = 0; k < NS; ++k)
            *reinterpret_cast<float4*>(&((float*)s_src)[s_loff[k]]) = ps[k];
        __syncthreads();

        // issue next chunk's global loads now; latency overlaps compute below
        if (ch + 1 < NCHUNK) {
            const float* tp = tgt + (ch + 1) * cstride;
            const float* sp = src + (ch + 1) * cstride;
            #pragma unroll
            for (int k = 0; k < NT; ++k)
                pt[k] = t_ok[k] ? *reinterpret_cast<const float4*>(tp + t_goff[k])
                                : make_float4(0.f, 0.f, 0.f, 0.f);
            #pragma unroll
            for (int k = 0; k < NS; ++k)
                ps[k] = *reinterpret_cast<const float4*>(sp + s_goff[k]);
        }

        // compute: per channel, 1 src b128 + 3 tgt b128 feed 36 FMAs
        #pragma unroll
        for (int c = 0; c < CC; ++c) {
            float4 sv = *reinterpret_cast<const float4*>(&s_src[c][ty][px0]);
            const float* row = &s_tgt[c][ty][px0];
            float4 w0 = *reinterpret_cast<const float4*>(row);
            float4 w1 = *reinterpret_cast<const float4*>(row + 4);
            float4 w2 = *reinterpret_cast<const float4*>(row + 8);
            float w[12] = {w0.x, w0.y, w0.z, w0.w,
                           w1.x, w1.y, w1.z, w1.w,
                           w2.x, w2.y, w2.z, w2.w};
            float s[4]  = {sv.x, sv.y, sv.z, sv.w};
            #pragma unroll
            for (int d = 0; d < 9; ++d) {
                acc[d].x += s[0] * w[d];
                acc[d].y += s[1] * w[d + 1];
                acc[d].z += s[2] * w[d + 2];
                acc[d].w += s[3] * w[d + 3];
            }
        }
    }

    // --- epilogue: 9 output channels (this dy), each pixel written exactly once
    const float inv = 1.0f / 81.0f;
    const int gy = y0 + ty;
    #pragma unroll
    for (int d = 0; d < 9; ++d) {
        int oc = chan_of(dy, d - 4);
        float4 o = make_float4(acc[d].x * inv, acc[d].y * inv,
                               acc[d].z * inv, acc[d].w * inv);
        *reinterpret_cast<float4*>(
            out + ((b * 81 + oc) * HGT + gy) * WID + x0 + px0) = o;
    }
}

extern "C" void kernel_launch(void* const* d_in, const int* in_sizes, int n_in,
                              void* d_out, int out_size, void* d_ws, size_t ws_size,
                              hipStream_t stream) {
    const float* src = (const float*)d_in[0];
    const float* tgt = (const float*)d_in[1];
    float* out = (float*)d_out;
    dim3 grid(WID / TILE, HGT / TILE, BATCH * 9);  // 5 x 3 x 36 = 540 blocks
    cost_volume_kernel<<<grid, dim3(THREADS, 1, 1), 0, stream>>>(src, tgt, out);
}

// Round 3
// 224.197 us; speedup vs baseline: 1.0860x; 1.0860x over previous
//
#include <hip/hip_runtime.h>

#define BATCH 4
#define CHAN 128
#define HGT 96
#define WID 160
#define TILE 32
#define CC 8
#define NCHUNK (CHAN / CC)   // 16
#define THREADS 256
#define TGT_W 44             // 40 used + 4 pad -> row stride 44: <=2-way bank aliasing (free)
#define NT 10                // tgt float4 stages/thread/chunk (8*32*10 / 256)

// Output channel index for displacement (dy,dx), matching _displacements(4) order.
__device__ __forceinline__ int chan_of(int dy, int dx) {
    if (dy == 0 && dx == 0) return 0;
    if (dx == 0) { int i = dy < 0 ? -dy : dy; return 1 + (i - 1) * 20 + (dy < 0 ? 0 : 1); }
    if (dy == 0) { int i = dx < 0 ? -dx : dx; return 1 + (i - 1) * 20 + (dx < 0 ? 2 : 3); }
    int i = dy < 0 ? -dy : dy;
    int j = dx < 0 ? -dx : dx;
    int s = (dy < 0) ? (dx < 0 ? 0 : 2) : (dx < 0 ? 3 : 1);
    return 1 + (i - 1) * 20 + 4 + (j - 1) * 4 + s;
}

// Pin exactly 2 waves/EU: caps VGPR budget at 256 and stops the allocator from
// spilling to chase higher occupancy (R2: 80 VGPRs + ~480MB scratch traffic).
__global__ __launch_bounds__(THREADS)
__attribute__((amdgpu_waves_per_eu(2, 2)))
void cost_volume_kernel(const float* __restrict__ src,
                        const float* __restrict__ tgt,
                        float* __restrict__ out) {
    __shared__ __align__(16) float s_tgt[CC][TILE][TGT_W];  // 45056 B, tgt tile only

    const int tid = threadIdx.x;
    const int tx  = tid & 7;          // 4 px each along x
    const int ty  = tid >> 3;         // 0..31
    const int px0 = tx * 4;
    const int x0  = blockIdx.x * TILE;
    const int y0  = blockIdx.y * TILE;
    const int b   = blockIdx.z / 9;
    const int dy  = (int)(blockIdx.z % 9) - 4;   // one dy per block

    // --- precompute tgt staging descriptors (divisions hoisted out of loop)
    int t_goff[NT], t_loff[NT];
    bool t_ok[NT];
    #pragma unroll
    for (int k = 0; k < NT; ++k) {
        int u   = k * THREADS + tid;   // 0..2559
        int q   = u % 10;              // float4 col within 40-wide row
        int rc  = u / 10;              // 0..255
        int c   = rc >> 5;             // 0..7
        int r   = rc & 31;
        int gy  = y0 + dy + r;
        int gx  = x0 - 4 + q * 4;
        t_ok[k] = ((unsigned)gy < (unsigned)HGT) && ((unsigned)gx < (unsigned)WID);
        int cy  = t_ok[k] ? gy : 0;
        int cx  = t_ok[k] ? gx : 0;
        t_goff[k] = ((b * CHAN + c) * HGT + cy) * WID + cx;
        t_loff[k] = (c * TILE + r) * TGT_W + q * 4;
    }
    // src: each thread reads only its own 4 pixels -> direct global loads, no LDS
    const int s_base = (b * CHAN * HGT + (y0 + ty)) * WID + (x0 + px0);
    const int cstride = HGT * WID;

    float4 acc[9];
    #pragma unroll
    for (int d = 0; d < 9; ++d) acc[d] = make_float4(0.f, 0.f, 0.f, 0.f);

    #pragma unroll 1
    for (int ch = 0; ch < NCHUNK; ++ch) {
        const int c0 = ch * CC;
        __syncthreads();   // previous chunk's consumers done
        #pragma unroll
        for (int k = 0; k < NT; ++k) {
            float4 v = t_ok[k]
                ? *reinterpret_cast<const float4*>(tgt + t_goff[k] + c0 * cstride)
                : make_float4(0.f, 0.f, 0.f, 0.f);
            *reinterpret_cast<float4*>(&((float*)s_tgt)[t_loff[k]]) = v;
        }
        // issue all 8 src loads up front; latency overlaps the LDS/FMA work below
        float4 sv[CC];
        #pragma unroll
        for (int c = 0; c < CC; ++c)
            sv[c] = *reinterpret_cast<const float4*>(src + s_base + (c0 + c) * cstride);
        __syncthreads();

        // compute: per channel, 3 LDS b128 (tgt window) + reg src feed 36 FMAs
        #pragma unroll
        for (int c = 0; c < CC; ++c) {
            const float* row = &s_tgt[c][ty][px0];
            float4 w0 = *reinterpret_cast<const float4*>(row);
            float4 w1 = *reinterpret_cast<const float4*>(row + 4);
            float4 w2 = *reinterpret_cast<const float4*>(row + 8);
            float w[12] = {w0.x, w0.y, w0.z, w0.w,
                           w1.x, w1.y, w1.z, w1.w,
                           w2.x, w2.y, w2.z, w2.w};
            float s[4]  = {sv[c].x, sv[c].y, sv[c].z, sv[c].w};
            #pragma unroll
            for (int d = 0; d < 9; ++d) {
                acc[d].x += s[0] * w[d];
                acc[d].y += s[1] * w[d + 1];
                acc[d].z += s[2] * w[d + 2];
                acc[d].w += s[3] * w[d + 3];
            }
        }
    }

    // --- epilogue: 9 output channels (this dy), each pixel written exactly once
    const float inv = 1.0f / 81.0f;
    const int gy = y0 + ty;
    #pragma unroll
    for (int d = 0; d < 9; ++d) {
        int oc = chan_of(dy, d - 4);
        float4 o = make_float4(acc[d].x * inv, acc[d].y * inv,
                               acc[d].z * inv, acc[d].w * inv);
        *reinterpret_cast<float4*>(
            out + ((b * 81 + oc) * HGT + gy) * WID + x0 + px0) = o;
    }
}

extern "C" void kernel_launch(void* const* d_in, const int* in_sizes, int n_in,
                              void* d_out, int out_size, void* d_ws, size_t ws_size,
                              hipStream_t stream) {
    const float* src = (const float*)d_in[0];
    const float* tgt = (const float*)d_in[1];
    float* out = (float*)d_out;
    dim3 grid(WID / TILE, HGT / TILE, BATCH * 9);  // 5 x 3 x 36 = 540 blocks
    cost_volume_kernel<<<grid, dim3(THREADS, 1, 1), 0, stream>>>(src, tgt, out);
}

// Round 4
// 183.573 us; speedup vs baseline: 1.3263x; 1.2213x over previous
//
#include <hip/hip_runtime.h>

#define BATCH 4
#define CHAN 128
#define HGT 96
#define WID 160
#define TILE_X 32
#define TILE_Y 16
#define THREADS 128
#define HW (HGT * WID)

// Output channel index for displacement (dy,dx), matching _displacements(4) order.
__device__ __forceinline__ int chan_of(int dy, int dx) {
    if (dy == 0 && dx == 0) return 0;
    if (dx == 0) { int i = dy < 0 ? -dy : dy; return 1 + (i - 1) * 20 + (dy < 0 ? 0 : 1); }
    if (dy == 0) { int i = dx < 0 ? -dx : dx; return 1 + (i - 1) * 20 + (dx < 0 ? 2 : 3); }
    int i = dy < 0 ? -dy : dy;
    int j = dx < 0 ? -dx : dx;
    int s = (dy < 0) ? (dx < 0 ? 0 : 2) : (dx < 0 ? 3 : 1);
    return 1 + (i - 1) * 20 + 4 + (j - 1) * 4 + s;
}

// Static zero pad target for x-edge lanes: they point here with stride 0.
// Module .data, never written, survives graph replay.
__device__ __align__(16) float g_zero4[4] = {0.f, 0.f, 0.f, 0.f};

__global__ __launch_bounds__(THREADS)
void cost_volume_kernel(const float* __restrict__ src,
                        const float* __restrict__ tgt,
                        float* __restrict__ out) {
    const int tid = threadIdx.x;
    const int tx  = tid & 7;          // 4 px each along x
    const int ty  = tid >> 3;         // 0..15
    const int px0 = tx * 4;
    const int x0  = blockIdx.x * TILE_X;
    const int y0  = blockIdx.y * TILE_Y;
    const int b   = blockIdx.z / 9;
    const int dy  = (int)(blockIdx.z % 9) - 4;   // one dy per block

    float4 acc[9];
    #pragma unroll
    for (int d = 0; d < 9; ++d) acc[d] = make_float4(0.f, 0.f, 0.f, 0.f);

    const int  row    = y0 + ty + dy;
    const bool row_ok = (unsigned)row < (unsigned)HGT;  // else all 9 outputs are 0
    const int  xb     = x0 + px0;
    const bool okL    = (xb >= 4);        // w0 float4 [xb-4..xb-1] in bounds?
    const bool okR    = (xb <= 152);      // w2 float4 [xb+4..xb+7] in bounds?

    if (row_ok) {
        const float* ps    = src + (b * CHAN * HGT + (y0 + ty)) * WID + xb;
        const float* tb    = tgt + (b * CHAN * HGT + row) * WID;
        const float* pL    = okL ? (tb + xb - 4) : g_zero4;
        const float* pM    = tb + xb;
        const float* pR    = okR ? (tb + xb + 4) : g_zero4;
        const int    stepL = okL ? HW : 0;   // OOB lanes re-read the zero block
        const int    stepR = okR ? HW : 0;

        #pragma unroll 4
        for (int c = 0; c < CHAN; ++c) {
            float4 sv = *reinterpret_cast<const float4*>(ps);
            float4 w0 = *reinterpret_cast<const float4*>(pL);
            float4 w1 = *reinterpret_cast<const float4*>(pM);
            float4 w2 = *reinterpret_cast<const float4*>(pR);
            ps += HW; pL += stepL; pM += HW; pR += stepR;

            float w[12] = {w0.x, w0.y, w0.z, w0.w,
                           w1.x, w1.y, w1.z, w1.w,
                           w2.x, w2.y, w2.z, w2.w};
            float s[4]  = {sv.x, sv.y, sv.z, sv.w};
            #pragma unroll
            for (int d = 0; d < 9; ++d) {
                acc[d].x += s[0] * w[d];
                acc[d].y += s[1] * w[d + 1];
                acc[d].z += s[2] * w[d + 2];
                acc[d].w += s[3] * w[d + 3];
            }
        }
    }

    // --- epilogue: 9 output channels (this dy), each pixel written exactly once
    const float inv = 1.0f / 81.0f;
    const int gy = y0 + ty;
    #pragma unroll
    for (int d = 0; d < 9; ++d) {
        int oc = chan_of(dy, d - 4);
        float4 o = make_float4(acc[d].x * inv, acc[d].y * inv,
                               acc[d].z * inv, acc[d].w * inv);
        *reinterpret_cast<float4*>(
            out + ((b * 81 + oc) * HGT + gy) * WID + xb) = o;
    }
}

extern "C" void kernel_launch(void* const* d_in, const int* in_sizes, int n_in,
                              void* d_out, int out_size, void* d_ws, size_t ws_size,
                              hipStream_t stream) {
    const float* src = (const float*)d_in[0];
    const float* tgt = (const float*)d_in[1];
    float* out = (float*)d_out;
    dim3 grid(WID / TILE_X, HGT / TILE_Y, BATCH * 9);  // 5 x 6 x 36 = 1080 blocks
    cost_volume_kernel<<<grid, dim3(THREADS, 1, 1), 0, stream>>>(src, tgt, out);
}

// Round 5
// 173.463 us; speedup vs baseline: 1.4036x; 1.0583x over previous
//
#include <hip/hip_runtime.h>

#define BATCH 4
#define CHAN 128
#define HGT 96
#define WID 160
#define TILE_X 32
#define TILE_Y 16
#define THREADS 128
#define HW (HGT * WID)
#define CG 8                 // channels per load group: 32 float4 loads in flight

// Output channel index for displacement (dy,dx), matching _displacements(4) order.
__device__ __forceinline__ int chan_of(int dy, int dx) {
    if (dy == 0 && dx == 0) return 0;
    if (dx == 0) { int i = dy < 0 ? -dy : dy; return 1 + (i - 1) * 20 + (dy < 0 ? 0 : 1); }
    if (dy == 0) { int i = dx < 0 ? -dx : dx; return 1 + (i - 1) * 20 + (dx < 0 ? 2 : 3); }
    int i = dy < 0 ? -dy : dy;
    int j = dx < 0 ? -dx : dx;
    int s = (dy < 0) ? (dx < 0 ? 0 : 2) : (dx < 0 ? 3 : 1);
    return 1 + (i - 1) * 20 + 4 + (j - 1) * 4 + s;
}

// Static zero pad target for x-edge lanes: they point here with stride 0.
__device__ __align__(16) float g_zero4[4] = {0.f, 0.f, 0.f, 0.f};

// Pin 2 waves/EU: the 1080-block grid supplies only ~2.1 waves/SIMD, so a
// bigger register budget costs nothing. R4's default allocation (40 VGPR,
// 8-wave target) starved memory-level parallelism; R3 proved (2,2) is
// honored without spill.
__global__ __launch_bounds__(THREADS)
__attribute__((amdgpu_waves_per_eu(2, 2)))
void cost_volume_kernel(const float* __restrict__ src,
                        const float* __restrict__ tgt,
                        float* __restrict__ out) {
    const int tid = threadIdx.x;
    const int tx  = tid & 7;          // 4 px each along x
    const int ty  = tid >> 3;         // 0..15
    const int px0 = tx * 4;
    const int x0  = blockIdx.x * TILE_X;
    const int y0  = blockIdx.y * TILE_Y;
    const int b   = blockIdx.z / 9;
    const int dy  = (int)(blockIdx.z % 9) - 4;   // one dy per block

    float4 acc[9];
    #pragma unroll
    for (int d = 0; d < 9; ++d) acc[d] = make_float4(0.f, 0.f, 0.f, 0.f);

    const int  row    = y0 + ty + dy;
    const bool row_ok = (unsigned)row < (unsigned)HGT;  // else all 9 outputs are 0
    const int  xb     = x0 + px0;
    const bool okL    = (xb >= 4);
    const bool okR    = (xb <= 152);

    if (row_ok) {
        const float* ps    = src + (b * CHAN * HGT + (y0 + ty)) * WID + xb;
        const float* tb    = tgt + (b * CHAN * HGT + row) * WID;
        const float* pL    = okL ? (tb + xb - 4) : g_zero4;
        const float* pM    = tb + xb;
        const float* pR    = okR ? (tb + xb + 4) : g_zero4;
        const int    stepL = okL ? HW : 0;   // OOB lanes re-read the zero block
        const int    stepR = okR ? HW : 0;

        #pragma unroll 1
        for (int cg = 0; cg < CHAN / CG; ++cg) {
            // --- phase 1: issue all 32 independent float4 loads (deep MLP)
            float4 sv[CG], w0[CG], w1[CG], w2[CG];
            #pragma unroll
            for (int c = 0; c < CG; ++c) {
                sv[c] = *reinterpret_cast<const float4*>(ps);
                w0[c] = *reinterpret_cast<const float4*>(pL);
                w1[c] = *reinterpret_cast<const float4*>(pM);
                w2[c] = *reinterpret_cast<const float4*>(pR);
                ps += HW; pL += stepL; pM += HW; pR += stepR;
            }
            // --- phase 2: 288 FMAs; compiler stages vmcnt waits per channel
            #pragma unroll
            for (int c = 0; c < CG; ++c) {
                float w[12] = {w0[c].x, w0[c].y, w0[c].z, w0[c].w,
                               w1[c].x, w1[c].y, w1[c].z, w1[c].w,
                               w2[c].x, w2[c].y, w2[c].z, w2[c].w};
                float s[4]  = {sv[c].x, sv[c].y, sv[c].z, sv[c].w};
                #pragma unroll
                for (int d = 0; d < 9; ++d) {
                    acc[d].x += s[0] * w[d];
                    acc[d].y += s[1] * w[d + 1];
                    acc[d].z += s[2] * w[d + 2];
                    acc[d].w += s[3] * w[d + 3];
                }
            }
        }
    }

    // --- epilogue: 9 output channels (this dy), each pixel written exactly once
    const float inv = 1.0f / 81.0f;
    const int gy = y0 + ty;
    #pragma unroll
    for (int d = 0; d < 9; ++d) {
        int oc = chan_of(dy, d - 4);
        float4 o = make_float4(acc[d].x * inv, acc[d].y * inv,
                               acc[d].z * inv, acc[d].w * inv);
        *reinterpret_cast<float4*>(
            out + ((b * 81 + oc) * HGT + gy) * WID + xb) = o;
    }
}

extern "C" void kernel_launch(void* const* d_in, const int* in_sizes, int n_in,
                              void* d_out, int out_size, void* d_ws, size_t ws_size,
                              hipStream_t stream) {
    const float* src = (const float*)d_in[0];
    const float* tgt = (const float*)d_in[1];
    float* out = (float*)d_out;
    dim3 grid(WID / TILE_X, HGT / TILE_Y, BATCH * 9);  // 5 x 6 x 36 = 1080 blocks
    cost_volume_kernel<<<grid, dim3(THREADS, 1, 1), 0, stream>>>(src, tgt, out);
}

// Round 6
// 151.213 us; speedup vs baseline: 1.6101x; 1.1471x over previous
//
#include <hip/hip_runtime.h>

#define BATCH 4
#define CHAN 128
#define HGT 96
#define WID 160
#define HW (HGT * WID)
#define THREADS 256
#define CG 4                 // channels per load group per wave-pair (16 b128 in flight)

// Output channel index for displacement (dy,dx), matching _displacements(4) order.
__device__ __forceinline__ int chan_of(int dy, int dx) {
    if (dy == 0 && dx == 0) return 0;
    if (dx == 0) { int i = dy < 0 ? -dy : dy; return 1 + (i - 1) * 20 + (dy < 0 ? 0 : 1); }
    if (dy == 0) { int i = dx < 0 ? -dx : dx; return 1 + (i - 1) * 20 + (dx < 0 ? 2 : 3); }
    int i = dy < 0 ? -dy : dy;
    int j = dx < 0 ? -dx : dx;
    int s = (dy < 0) ? (dx < 0 ? 0 : 2) : (dx < 0 ? 3 : 1);
    return 1 + (i - 1) * 20 + 4 + (j - 1) * 4 + s;
}

// Static zero pad target for x-edge lanes: they point here with stride 0.
__device__ __align__(16) float g_zero4[4] = {0.f, 0.f, 0.f, 0.f};

// 4 waves/EU pinned: grid supplies 1080 blocks x 4 waves / 256 CU = 16.9
// waves/CU = 4.2/SIMD. Budget 128 VGPR/wave; CG=4 keeps ~16 loads in
// flight/wave without spilling (R2 spill lesson: watch WRITE_SIZE).
__global__ __launch_bounds__(THREADS)
__attribute__((amdgpu_waves_per_eu(4, 4)))
void cost_volume_kernel(const float* __restrict__ src,
                        const float* __restrict__ tgt,
                        float* __restrict__ out) {
    __shared__ __align__(16) float4 s_comb[9][128];  // 18432 B combine buffer

    const int tid  = threadIdx.x;
    const int lid  = tid & 127;       // pixel-lane within the 32x16 tile
    const int half = tid >> 7;        // channel half: 0 -> ch 0..63, 1 -> 64..127
    const int tx   = lid & 7;         // 4 px each along x
    const int ty   = lid >> 3;        // 0..15
    const int px0  = tx * 4;

    // --- XCD-affinity swizzle: blockIdx%8 selects a (batch, y-half) slab so
    // all blocks resident on one XCD stream the same 8MB slab through its L2.
    const int w    = blockIdx.x;      // 0..1079
    const int slab = w & 7;
    const int b    = slab >> 1;
    const int yh   = slab & 1;
    const int r    = w >> 3;          // 0..134
    const int dy   = r % 9 - 4;
    const int t    = r / 9;           // 0..14
    const int x0   = (t % 5) * 32;
    const int y0   = (yh * 3 + t / 5) * 16;

    float4 acc[9];
    #pragma unroll
    for (int d = 0; d < 9; ++d) acc[d] = make_float4(0.f, 0.f, 0.f, 0.f);

    const int  row    = y0 + ty + dy;
    const bool row_ok = (unsigned)row < (unsigned)HGT;  // else contribution is 0
    const int  xb     = x0 + px0;
    const bool okL    = (xb >= 4);
    const bool okR    = (xb <= 152);
    const int  c0     = half * (CHAN / 2);

    if (row_ok) {
        const float* ps    = src + ((b * CHAN + c0) * HGT + (y0 + ty)) * WID + xb;
        const float* tb    = tgt + ((b * CHAN + c0) * HGT + row) * WID;
        const float* pL    = okL ? (tb + xb - 4) : g_zero4;
        const float* pM    = tb + xb;
        const float* pR    = okR ? (tb + xb + 4) : g_zero4;
        const int    stepL = okL ? HW : 0;   // OOB lanes re-read the zero block
        const int    stepR = okR ? HW : 0;

        #pragma unroll 1
        for (int cg = 0; cg < (CHAN / 2) / CG; ++cg) {
            // phase 1: 16 independent b128 loads in flight
            float4 sv[CG], w0[CG], w1[CG], w2[CG];
            #pragma unroll
            for (int c = 0; c < CG; ++c) {
                sv[c] = *reinterpret_cast<const float4*>(ps);
                w0[c] = *reinterpret_cast<const float4*>(pL);
                w1[c] = *reinterpret_cast<const float4*>(pM);
                w2[c] = *reinterpret_cast<const float4*>(pR);
                ps += HW; pL += stepL; pM += HW; pR += stepR;
            }
            // phase 2: 144 FMAs
            #pragma unroll
            for (int c = 0; c < CG; ++c) {
                float wv[12] = {w0[c].x, w0[c].y, w0[c].z, w0[c].w,
                                w1[c].x, w1[c].y, w1[c].z, w1[c].w,
                                w2[c].x, w2[c].y, w2[c].z, w2[c].w};
                float s[4]   = {sv[c].x, sv[c].y, sv[c].z, sv[c].w};
                #pragma unroll
                for (int d = 0; d < 9; ++d) {
                    acc[d].x += s[0] * wv[d];
                    acc[d].y += s[1] * wv[d + 1];
                    acc[d].z += s[2] * wv[d + 2];
                    acc[d].w += s[3] * wv[d + 3];
                }
            }
        }
    }

    // --- combine the two channel halves through LDS (all threads reach barrier)
    if (half) {
        #pragma unroll
        for (int d = 0; d < 9; ++d) s_comb[d][lid] = acc[d];
    }
    __syncthreads();
    if (!half) {
        const float inv = 1.0f / 81.0f;
        const int gy = y0 + ty;
        #pragma unroll
        for (int d = 0; d < 9; ++d) {
            float4 p = s_comb[d][lid];
            int oc = chan_of(dy, d - 4);
            float4 o = make_float4((acc[d].x + p.x) * inv, (acc[d].y + p.y) * inv,
                                   (acc[d].z + p.z) * inv, (acc[d].w + p.w) * inv);
            *reinterpret_cast<float4*>(
                out + ((b * 81 + oc) * HGT + gy) * WID + xb) = o;
        }
    }
}

extern "C" void kernel_launch(void* const* d_in, const int* in_sizes, int n_in,
                              void* d_out, int out_size, void* d_ws, size_t ws_size,
                              hipStream_t stream) {
    const float* src = (const float*)d_in[0];
    const float* tgt = (const float*)d_in[1];
    float* out = (float*)d_out;
    cost_volume_kernel<<<dim3(1080, 1, 1), dim3(THREADS, 1, 1), 0, stream>>>(src, tgt, out);
}